// Round 4
// baseline (146.501 us; speedup 1.0000x reference)
//
#include <hip/hip_runtime.h>

// Modulated deformable depthwise conv, B=8 C=128 H=W=64 K=3 PAD=1 STRIDE=1.
// Round 3: fix round 2's global_load_lds misuse. The DMA's LDS dest is
// wave-uniform-base + lane*4 (m104), so the exec mask must be dense /
// lane-prefix with lane-consecutive idx. We DMA EVERY cell from a CLAMPED
// global address (no data-dependent masking); out-of-image corners are
// handled by zeroing that corner's bilinear weight (round-0 style), so
// pad-cell garbage is multiplied by 0. LDS cell = float4 of 4 channels ->
// each bilinear corner is ONE ds_read_b128 serving 4 channels.

#define BB 8
#define CC 128
#define HH 64
#define WW 64
#define HWs (HH*WW)
#define KKT 9
#define CH 8               // channels per block
#define NCG (CC/CH)        // 16
#define CPI 4              // channels interleaved per LDS buffer
#define NIT (CH/CPI)       // 2
#define ROWS 8
#define NHS (HH/ROWS)      // 8
#define WLO 6
#define WR  22
#define CLO 6
#define WC  76
#define CELLS (WR*WC)      // 1672
#define CPAD  1680         // float4 slots per buffer (26.25 KB)
#define NTHR 512
#define EPB (CELLS*CPI)    // 6688 floats per buffer
#define NK  ((EPB + NTHR - 1)/NTHR)   // 14

__global__ __launch_bounds__(NTHR, 6)
void mdcn_kernel(const float* __restrict__ x,
                 const float* __restrict__ offset,
                 const float* __restrict__ mask,
                 const float* __restrict__ dynw,
                 float* __restrict__ out)
{
    __shared__ float4 lds[2][CPAD];   // 52.5 KB total

    const int blk = blockIdx.x;
    const int hs = blk & (NHS - 1);
    const int cg = (blk >> 3) & (NCG - 1);
    const int b  = blk >> 7;
    const int tid = threadIdx.x;
    const int w = tid & 63;
    const int h0 = hs * ROWS;
    const int h = h0 + (tid >> 6);

    const float* xg = x + (size_t)(b * CC + cg * CH) * HWs;

    // ---- dense DMA stage: every lane active, idx lane-consecutive ----
    // (tail `idx < EPB` is a pure-tid lane-prefix of wave 0: safe)
    #define STAGE(DST, XP)                                                     \
    do {                                                                       \
        float* Lb_ = (float*)&lds[DST][0];                                     \
        const float* xp_ = (XP);                                               \
        _Pragma("unroll")                                                      \
        for (int k = 0; k < NK; ++k) {                                         \
            const int idx = tid + k * NTHR;                                    \
            if (idx < EPB) {                                                   \
                const int cell = idx >> 2;                                     \
                const int ch   = idx & 3;                                      \
                const int row  = cell / WC;                                    \
                const int col  = cell - row * WC;                              \
                const int ar   = min(max(h0 - WLO + row, 0), HH - 1);          \
                const int ac   = min(max(col - CLO, 0), WW - 1);               \
                __builtin_amdgcn_global_load_lds(                              \
                    (const __attribute__((address_space(1))) void*)            \
                        (xp_ + ch * HWs + ar * WW + ac),                       \
                    (__attribute__((address_space(3))) void*)(Lb_ + idx),      \
                    4, 0, 0);                                                  \
            }                                                                  \
        }                                                                      \
    } while (0)

    // prologue: stage channels 0..3 into buf0
    STAGE(0, xg);

    // ---- per-tap metadata (channel-invariant) — overlaps DMA latency ----
    float fw[KKT][4];
    int   woff[KKT];
    int   badmask = 0;
    const float* offp = offset + (size_t)b * (2 * KKT) * HWs + h * WW + w;
    const float* mskp = mask   + (size_t)b * KKT * HWs       + h * WW + w;
    #pragma unroll
    for (int t = 0; t < KKT; ++t) {
        const float oy = offp[(2 * t)     * HWs];
        const float ox = offp[(2 * t + 1) * HWs];
        const float m  = mskp[t * HWs];
        const float py = (float)(h - 1 + t / 3) + oy;
        const float px = (float)(w - 1 + t % 3) + ox;
        const float fy = floorf(py), fx = floorf(px);
        const float dy = py - fy,    dx = px - fx;
        const int y0 = (int)fy, x0 = (int)fx;
        const bool inwin = (y0 >= h0 - WLO) && (y0 <= h0 - WLO + WR - 2) &&
                           (x0 >= -CLO)     && (x0 <= -CLO + WC - 2);
        if (!inwin) {
            badmask |= (1 << t);
            woff[t] = 0;
            fw[t][0] = fw[t][1] = fw[t][2] = fw[t][3] = 0.f;
        } else {
            woff[t] = (y0 - (h0 - WLO)) * WC + (x0 + CLO);
            const bool vy0 = (unsigned)y0       < (unsigned)HH;
            const bool vy1 = (unsigned)(y0 + 1) < (unsigned)HH;
            const bool vx0 = (unsigned)x0       < (unsigned)WW;
            const bool vx1 = (unsigned)(x0 + 1) < (unsigned)WW;
            const float omdy = 1.f - dy, omdx = 1.f - dx;
            fw[t][0] = (vy0 && vx0) ? omdy * omdx * m : 0.f;
            fw[t][1] = (vy0 && vx1) ? omdy * dx   * m : 0.f;
            fw[t][2] = (vy1 && vx0) ? dy   * omdx * m : 0.f;
            fw[t][3] = (vy1 && vx1) ? dy   * dx   * m : 0.f;
        }
    }
    const int anybad = __any(badmask != 0);

    __syncthreads();   // buf0 DMA drained (compiler emits vmcnt(0) at barrier)

    const float* wtb  = dynw + (size_t)(b * CC + cg * CH) * KKT;
    float*       outp = out  + (size_t)(b * CC + cg * CH) * HWs + h * WW + w;

    for (int it = 0; it < NIT; ++it) {
        if (it + 1 < NIT) {
            STAGE((it + 1) & 1, xg + (size_t)(it + 1) * CPI * HWs);
        }

        const float4* Lp = &lds[it & 1][0];
        const float*  wt = wtb + it * CPI * KKT;
        float s0 = 0.f, s1 = 0.f, s2 = 0.f, s3 = 0.f;

        #pragma unroll
        for (int t = 0; t < KKT; ++t) {
            const float4 c00 = Lp[woff[t]];
            const float4 c01 = Lp[woff[t] + 1];
            const float4 c10 = Lp[woff[t] + WC];
            const float4 c11 = Lp[woff[t] + WC + 1];
            const float w00 = fw[t][0], w01 = fw[t][1];
            const float w10 = fw[t][2], w11 = fw[t][3];
            const float v0 = c00.x * w00 + c01.x * w01 + c10.x * w10 + c11.x * w11;
            const float v1 = c00.y * w00 + c01.y * w01 + c10.y * w10 + c11.y * w11;
            const float v2 = c00.z * w00 + c01.z * w01 + c10.z * w10 + c11.z * w11;
            const float v3 = c00.w * w00 + c01.w * w01 + c10.w * w10 + c11.w * w11;
            s0 += v0 * wt[0 * KKT + t];
            s1 += v1 * wt[1 * KKT + t];
            s2 += v2 * wt[2 * KKT + t];
            s3 += v3 * wt[3 * KKT + t];
        }

        // rare corrective path for out-of-window taps (exact reference math)
        if (anybad) {
            #pragma unroll
            for (int t = 0; t < KKT; ++t) {
                if (badmask & (1 << t)) {
                    const float oy = offp[(2 * t)     * HWs];
                    const float ox = offp[(2 * t + 1) * HWs];
                    const float m  = mskp[t * HWs];
                    const float py = (float)(h - 1 + t / 3) + oy;
                    const float px = (float)(w - 1 + t % 3) + ox;
                    const float fy = floorf(py), fx = floorf(px);
                    const float dy = py - fy, dx = px - fx;
                    const int y0 = (int)fy, x0 = (int)fx;
                    const int y1 = y0 + 1,  x1 = x0 + 1;
                    const int cy0 = min(max(y0, 0), HH - 1);
                    const int cy1 = min(max(y1, 0), HH - 1);
                    const int cx0 = min(max(x0, 0), WW - 1);
                    const int cx1 = min(max(x1, 0), WW - 1);
                    const float m00 = ((unsigned)y0 < HH && (unsigned)x0 < WW) ? 1.f : 0.f;
                    const float m01 = ((unsigned)y0 < HH && (unsigned)x1 < WW) ? 1.f : 0.f;
                    const float m10 = ((unsigned)y1 < HH && (unsigned)x0 < WW) ? 1.f : 0.f;
                    const float m11 = ((unsigned)y1 < HH && (unsigned)x1 < WW) ? 1.f : 0.f;
                    const float omdy = 1.f - dy, omdx = 1.f - dx;
                    #pragma unroll
                    for (int c = 0; c < CPI; ++c) {
                        const float* pl = xg + (size_t)(it * CPI + c) * HWs;
                        const float v = pl[cy0 * WW + cx0] * m00 * (omdy * omdx)
                                      + pl[cy0 * WW + cx1] * m01 * (omdy * dx)
                                      + pl[cy1 * WW + cx0] * m10 * (dy * omdx)
                                      + pl[cy1 * WW + cx1] * m11 * (dy * dx);
                        const float add = v * m * wt[c * KKT + t];
                        if      (c == 0) s0 += add;
                        else if (c == 1) s1 += add;
                        else if (c == 2) s2 += add;
                        else             s3 += add;
                    }
                }
            }
        }

        outp[(size_t)(it * CPI + 0) * HWs] = s0;
        outp[(size_t)(it * CPI + 1) * HWs] = s1;
        outp[(size_t)(it * CPI + 2) * HWs] = s2;
        outp[(size_t)(it * CPI + 3) * HWs] = s3;

        if (it + 1 < NIT) __syncthreads();   // next buffer's DMA drained
    }
    #undef STAGE
}

extern "C" void kernel_launch(void* const* d_in, const int* in_sizes, int n_in,
                              void* d_out, int out_size, void* d_ws, size_t ws_size,
                              hipStream_t stream) {
    const float* x      = (const float*)d_in[0];
    const float* offset = (const float*)d_in[1];
    const float* mask   = (const float*)d_in[2];
    const float* dynw   = (const float*)d_in[3];
    float* out = (float*)d_out;

    dim3 grid(BB * NCG * NHS);   // 8 * 16 * 8 = 1024 blocks
    dim3 block(NTHR);
    mdcn_kernel<<<grid, block, 0, stream>>>(x, offset, mask, dynw, out);
}